// Round 3
// baseline (183.540 us; speedup 1.0000x reference)
//
#include <hip/hip_runtime.h>
#include <math.h>

// RankingLoss = mean over rows of  sum_{pairs: lab_a - lab_b > TOL} lsig(lg_a - lg_b)
//
// Exact decomposition (per row, unordered pairs {i,j}, d = lg_i - lg_j, s = sign of
// label order, valid = |ld| > TOL):
//   lsig(s·d) = min(s·d,0) - log1p(e^{-|d|});  min(s·d,0) = (s·d - |d|)/2
//   row = 1/2·T1 - 1/2·(T2all - T2inv) - (Sall - Sinv)
//     T1    = sum_i lg_i · c_i,  c_i = #{j: lab_i-lab_j>TOL} - #{j: lab_j-lab_i>TOL}
//     T2all = sum_{all pairs} |d|  (from logit ranks)
//     T2inv = sum_{invalid pairs} |d|        (windowed, labels sorted)
//     Sall  = sum_{all pairs} log1p(e^{-|d|})   <-- the only O(N^2) term, MASK-FREE
//     Sinv  = sum_{invalid pairs} log1p(e^{-|d|}) (windowed)
// Phase A (blocks 0..63): per-row bitonic sorts + searches + window terms (exact, f64).
// Phase B (blocks 64..2111): Sall via circulant pairs k=1..1024 (k=1024 half-weight),
//   log2-domain product-of-4 trick: per pair sub + exp2(-|.|) + fma, 1/4 log.

#define NN 2048
#define BB 64
#define TOL 0.01f
#define BLK 256
#define BGRID (BB * 32)          // 2048 phase-B blocks
#define GRID (BB + BGRID)        // 2112
#define LOG2E 1.4426950408889634f
#define LN2 0.6931471805599453

__device__ float  g_partB[BGRID];
__device__ double g_partA[BB];

__global__ __launch_bounds__(BLK) void rank_main(const float* __restrict__ logits,
                                                 const float* __restrict__ labels) {
    __shared__ float4 smem4[NN / 2];     // 16 KB, aliased per phase
    __shared__ float  swv[4];
    const int bid = blockIdx.x;

    if (bid < BB) {
        // ---------------- Phase A: exact side terms for one row ----------------
        float2* srt = (float2*)smem4;    // (.x = label, .y = logit)
        const int row = bid;
        const float* lg = logits + (size_t)row * NN;
        const float* lb = labels + (size_t)row * NN;
        for (int x = threadIdx.x; x < NN; x += BLK)
            srt[x] = make_float2(lb[x], lg[x]);
        __syncthreads();

        // bitonic sort ascending by label (.x)
        for (int size = 2; size <= NN; size <<= 1)
            for (int stride = size >> 1; stride >= 1; stride >>= 1) {
                for (int s = threadIdx.x; s < NN / 2; s += BLK) {
                    int i = ((s & ~(stride - 1)) << 1) | (s & (stride - 1));
                    int j = i | stride;
                    float2 a = srt[i], b = srt[j];
                    bool up = ((i & size) == 0);
                    if ((a.x > b.x) == up) { srt[i] = b; srt[j] = a; }
                }
                __syncthreads();
            }

        double acc = 0.0;
        for (int k = threadIdx.x; k < NN; k += BLK) {
            float labk = srt[k].x;
            float lgtk = srt[k].y;
            // count below: # m with labk - srt[m].x > TOL (true for m < lo)
            int lo = 0, hi = NN;
            while (lo < hi) { int mid = (lo + hi) >> 1;
                if (labk - srt[mid].x > TOL) lo = mid + 1; else hi = mid; }
            int cl = lo;
            // count above: # m with srt[m].x - labk > TOL (true for m >= lo2)
            lo = 0; hi = NN;
            while (lo < hi) { int mid = (lo + hi) >> 1;
                if (srt[mid].x - labk > TOL) hi = mid; else lo = mid + 1; }
            int ch = NN - lo;
            acc += 0.5 * (double)lgtk * (double)(cl - ch);          // +1/2 T1
            // invalid window: pairs (k,m), m>k, srt[m].x - labk <= TOL
            for (int m = k + 1; m < NN; ++m) {
                if (srt[m].x - labk > TOL) break;
                float dd = fabsf(lgtk - srt[m].y);
                acc += 0.5 * (double)dd + (double)log1pf(__expf(-dd)); // +1/2 T2inv + Sinv
            }
        }
        __syncthreads();

        // re-sort in place by logit (.y) ascending for rank weights
        for (int size = 2; size <= NN; size <<= 1)
            for (int stride = size >> 1; stride >= 1; stride >>= 1) {
                for (int s = threadIdx.x; s < NN / 2; s += BLK) {
                    int i = ((s & ~(stride - 1)) << 1) | (s & (stride - 1));
                    int j = i | stride;
                    float2 a = srt[i], b = srt[j];
                    bool up = ((i & size) == 0);
                    if ((a.y > b.y) == up) { srt[i] = b; srt[j] = a; }
                }
                __syncthreads();
            }
        for (int k = threadIdx.x; k < NN; k += BLK)
            acc -= 0.5 * (double)srt[k].y * (double)(2 * k - (NN - 1)); // -1/2 T2all
        __syncthreads();

        for (int off = 32; off > 0; off >>= 1) acc += __shfl_down(acc, off);
        double* dsc = (double*)smem4;
        if ((threadIdx.x & 63) == 0) dsc[threadIdx.x >> 6] = acc;
        __syncthreads();
        if (threadIdx.x == 0) g_partA[row] = dsc[0] + dsc[1] + dsc[2] + dsc[3];
    } else {
        // ---------------- Phase B: Sall (mask-free O(N^2) core) ----------------
        float* spj = (float*)smem4;
        const int b = bid - BB;
        const int row = b >> 5;
        const int sub = b & 31;
        const int ic = sub >> 2;     // 0..7
        const int kc = sub & 3;      // 0..3
        const float* lg = logits + (size_t)row * NN;
        const int ibeg = ic * BLK;
        const int kbeg = kc * 256 + 1;
        const int jbeg = ibeg + kbeg;

        for (int x = threadIdx.x; x < 512; x += BLK)
            spj[x] = lg[(jbeg + x) & (NN - 1)] * LOG2E;
        __syncthreads();

        const float li = lg[ibeg + threadIdx.x] * LOG2E;
        float accL = 0.0f;           // sum of log2(prod(1 + 2^{-|d|}))
#pragma unroll 2
        for (int kk = 0; kk < 256; kk += 8) {
            float p0 = 1.0f, p1 = 1.0f;
#pragma unroll
            for (int u = 0; u < 4; ++u) {
                float t0 = __builtin_amdgcn_exp2f(-fabsf(li - spj[threadIdx.x + kk + u]));
                float t1 = __builtin_amdgcn_exp2f(-fabsf(li - spj[threadIdx.x + kk + 4 + u]));
                p0 = fmaf(t0, p0, p0);
                p1 = fmaf(t1, p1, p1);
            }
            accL += __builtin_amdgcn_logf(p0) + __builtin_amdgcn_logf(p1);
        }
        if (kc == 3) {
            // k=1024 pairs visited from both endpoints: remove surplus half
            float t = __builtin_amdgcn_exp2f(-fabsf(li - spj[threadIdx.x + 255]));
            accL -= 0.5f * __builtin_amdgcn_logf(1.0f + t);
        }

        float v = accL;
        for (int off = 32; off > 0; off >>= 1) v += __shfl_down(v, off);
        if ((threadIdx.x & 63) == 0) swv[threadIdx.x >> 6] = v;
        __syncthreads();
        if (threadIdx.x == 0) g_partB[b] = swv[0] + swv[1] + swv[2] + swv[3];
    }
}

__global__ __launch_bounds__(BLK) void rank_final(float* __restrict__ out) {
    double accB = 0.0, acc = 0.0;
    for (int i = threadIdx.x; i < BGRID; i += BLK) accB += (double)g_partB[i];
    acc = -LN2 * accB;                       // -Sall  (natural log units)
    for (int i = threadIdx.x; i < BB; i += BLK) acc += g_partA[i];
    for (int off = 32; off > 0; off >>= 1) acc += __shfl_down(acc, off);
    __shared__ double sw[4];
    if ((threadIdx.x & 63) == 0) sw[threadIdx.x >> 6] = acc;
    __syncthreads();
    if (threadIdx.x == 0)
        out[0] = (float)((sw[0] + sw[1] + sw[2] + sw[3]) / (double)BB);
}

extern "C" void kernel_launch(void* const* d_in, const int* in_sizes, int n_in,
                              void* d_out, int out_size, void* d_ws, size_t ws_size,
                              hipStream_t stream) {
    const float* logits = (const float*)d_in[0];
    const float* labels = (const float*)d_in[1];
    float* out = (float*)d_out;
    (void)in_sizes; (void)n_in; (void)out_size; (void)d_ws; (void)ws_size;

    rank_main<<<GRID, BLK, 0, stream>>>(logits, labels);
    rank_final<<<1, BLK, 0, stream>>>(out);
}

// Round 4
// 38.694 us; speedup vs baseline: 4.7434x; 4.7434x over previous
//
#include <hip/hip_runtime.h>

// RankingLoss: mean over rows of sum over ordered pairs (label_i-label_j>TOL)
// of log_sigmoid(logit_i - logit_j).
//
// Per unordered pair, ds = (lg_i-lg_j)*log2e, ld = lab_i-lab_j:
//   contribution = -ln2 * log2(1 + 2^a),  a = (ld>0 ? -ds : +ds),  masked to 0
//   when |ld| <= TOL. Orientation uses sign(ld) (don't-care inside the band
//   since the term is masked) -> a = ds_rev XOR signbit(ld), ds_rev = -ds.
// Accumulate log2 of products of 8 terms (each in [1,2], prod <= 256).
//
// Pairs: circulant j=(i+k) mod N, k in [1,1024]; k in [1,1023] hits each
// unordered pair once, k=1024 twice -> subtract half of the k=1024 term.

#define NN 2048
#define BB 64
#define TOL 0.01f
#define BLK 256
#define KCHUNKS 8                    // k-chunks of 128
#define ICHUNKS 8                    // i-chunks of 256
#define NBLK_PER_ROW (KCHUNKS * ICHUNKS)   // 64
#define GRID (BB * NBLK_PER_ROW)           // 4096
#define LOG2E 1.4426950408889634f

__device__ float g_partials[GRID];

__global__ __launch_bounds__(BLK) void rank_main(const float* __restrict__ logits,
                                                 const float* __restrict__ labels) {
    __shared__ float2 spj[384];      // 3 KB window
    const int bid = blockIdx.x;
    const int row = bid >> 6;
    const int sub = bid & 63;
    const int ic = sub >> 3;         // 0..7
    const int kc = sub & 7;          // 0..7

    const float* lg = logits + (size_t)row * NN;
    const float* lb = labels + (size_t)row * NN;
    const int ibeg = ic * BLK;
    const int kbeg = kc * 128 + 1;
    const int jbeg = ibeg + kbeg;

    for (int x = threadIdx.x; x < 384; x += BLK) {
        int j = (jbeg + x) & (NN - 1);
        spj[x] = make_float2(lg[j] * LOG2E, lb[j]);
    }
    __syncthreads();

    const int i = ibeg + threadIdx.x;
    const float li_s = lg[i] * LOG2E;
    const float lai  = lb[i];

    float accL = 0.0f;
#pragma unroll 2
    for (int kk0 = 0; kk0 < 128; kk0 += 8) {
        float prod = 1.0f;
#pragma unroll
        for (int u = 0; u < 8; ++u) {
            float2 pj = spj[threadIdx.x + kk0 + u];
            float ds_rev = pj.x - li_s;               // = -ds
            float ld     = lai - pj.y;
            unsigned au = __float_as_uint(ds_rev) ^
                          (__float_as_uint(ld) & 0x80000000u);
            float t  = __builtin_amdgcn_exp2f(__uint_as_float(au));
            float tm = (fabsf(ld) > TOL) ? t : 0.0f;
            prod = fmaf(tm, prod, prod);              // prod *= (1 + tm)
        }
        accL += __builtin_amdgcn_logf(prod);          // v_log_f32 = log2
    }
    if (kc == KCHUNKS - 1) {
        // k=1024 (kk=127) visited at full weight from both endpoints; each
        // visit should count half -> remove the surplus half here.
        float2 pj = spj[threadIdx.x + 127];
        float ds_rev = pj.x - li_s;
        float ld     = lai - pj.y;
        unsigned au = __float_as_uint(ds_rev) ^
                      (__float_as_uint(ld) & 0x80000000u);
        float t  = __builtin_amdgcn_exp2f(__uint_as_float(au));
        float tm = (fabsf(ld) > TOL) ? t : 0.0f;
        accL -= 0.5f * __builtin_amdgcn_logf(1.0f + tm);
    }

    float v = -0.69314718055994531f * accL;

    for (int off = 32; off > 0; off >>= 1) v += __shfl_down(v, off);
    __shared__ float swave[BLK / 64];
    const int wid  = threadIdx.x >> 6;
    const int lane = threadIdx.x & 63;
    if (lane == 0) swave[wid] = v;
    __syncthreads();
    if (threadIdx.x == 0)
        g_partials[bid] = swave[0] + swave[1] + swave[2] + swave[3];
}

__global__ __launch_bounds__(BLK) void rank_final(float* __restrict__ out) {
    float v = 0.0f;
    for (int idx = threadIdx.x; idx < GRID; idx += BLK) v += g_partials[idx];
    for (int off = 32; off > 0; off >>= 1) v += __shfl_down(v, off);
    __shared__ float swave[BLK / 64];
    const int wid  = threadIdx.x >> 6;
    const int lane = threadIdx.x & 63;
    if (lane == 0) swave[wid] = v;
    __syncthreads();
    if (threadIdx.x == 0)
        out[0] = (swave[0] + swave[1] + swave[2] + swave[3]) * (1.0f / BB);
}

extern "C" void kernel_launch(void* const* d_in, const int* in_sizes, int n_in,
                              void* d_out, int out_size, void* d_ws, size_t ws_size,
                              hipStream_t stream) {
    const float* logits = (const float*)d_in[0];
    const float* labels = (const float*)d_in[1];
    float* out = (float*)d_out;
    (void)in_sizes; (void)n_in; (void)out_size; (void)d_ws; (void)ws_size;

    rank_main<<<GRID, BLK, 0, stream>>>(logits, labels);
    rank_final<<<1, BLK, 0, stream>>>(out);
}